// Round 1
// baseline (8529.675 us; speedup 1.0000x reference)
//
#include <hip/hip_runtime.h>

typedef __attribute__((ext_vector_type(4))) float f32x4;
typedef __attribute__((ext_vector_type(2))) float f32x2;
typedef __attribute__((ext_vector_type(8))) short s16x8;

static __device__ __forceinline__ unsigned short f2bf(float f) {
  unsigned int u = __builtin_bit_cast(unsigned int, f);
  u += 0x7fffu + ((u >> 16) & 1u);   // round-to-nearest-even
  return (unsigned short)(u >> 16);
}

// ---------------- degree / dinv ----------------
__global__ void deg_init_k(int* deg, int N) {
  int i = blockIdx.x * 256 + threadIdx.x;
  if (i < N) deg[i] = 1;              // self-loop
}
__global__ void deg_count_k(const int* __restrict__ edges, int* deg, int E) {
  int e = blockIdx.x * 256 + threadIdx.x;
  if (e < E) atomicAdd(&deg[edges[E + e]], 1);
}
__global__ void dinv_k(const int* __restrict__ deg, float* dinv, int N) {
  int i = blockIdx.x * 256 + threadIdx.x;
  if (i < N) dinv[i] = rsqrtf((float)deg[i]);
}

// ---------------- weight transpose + bf16 convert: Wt[n][k] = bf16(W[k][n]) ----------------
__global__ void convw_k(const float* __restrict__ W, unsigned short* __restrict__ Wt, int K, int Nn) {
  int t = blockIdx.x * 256 + threadIdx.x;
  if (t < K * Nn) {
    int n = t / K;
    int k = t - n * K;
    Wt[n * K + k] = f2bf(W[(long long)k * Nn + n]);
  }
}

// ---------------- bf16 MFMA GEMM: C[M][NTOT] = op(A)[M][KTOT] @ Bt^T ----------------
// MODE 0: a = A[m][k]            (layer-1: A = x)
// MODE 1: a = relu(bias[k] + dinv[m]*A[m][k])   (layer-2: A = acc1)
// Epilogue: g[m][n] = acc[m][n][n] = dinv[m] * C[m][n], written to BOTH outg and outacc
// (outacc is the scatter destination seeded with the self-loop term).
template <int KTOT, int NTOT, int MODE>
__global__ __launch_bounds__(256, 2) void gemm_k(
    const float* __restrict__ A, const unsigned short* __restrict__ Bt,
    const float* __restrict__ bias, const float* __restrict__ dinv,
    float* __restrict__ outg, float* __restrict__ outacc, int M) {
  constexpr int BM = 128, BK = 32, LD = BK + 8;   // +8 bf16 pad (16B) kills bank conflicts
  constexpr int STRIP = NTOT / 4;                 // cols per wave
  constexpr int NF = STRIP / 16;                  // 16-wide col frags per wave
  constexpr int CH = NTOT / 64;                   // B-staging chunks per thread

  __shared__ unsigned short Asm_[BM * LD];
  __shared__ unsigned short Bsm_[NTOT * LD];

  const int tid = threadIdx.x;
  const int wave = tid >> 6;
  const int lane = tid & 63;
  const int fr = lane & 15;
  const int quad = lane >> 4;
  const int m0 = blockIdx.x * BM;

  f32x4 acc[8][NF];
#pragma unroll
  for (int i = 0; i < 8; ++i)
#pragma unroll
    for (int j = 0; j < NF; ++j) { f32x4 z = {0.f, 0.f, 0.f, 0.f}; acc[i][j] = z; }

  const int sr = tid >> 1;            // A-staging row
  const int sc = (tid & 1) << 4;      // A-staging col (0/16)
  const bool arow_ok = (m0 + sr) < M;
  const float dv_a = (MODE == 1 && arow_ok) ? dinv[m0 + sr] : 0.0f;
  const float* arow = A + (long long)(m0 + sr) * KTOT;

  auto loadA = [&](int k0, float* va) {
    if (arow_ok) {
      const f32x4* p = (const f32x4*)(arow + k0 + sc);
      f32x4 v0 = p[0], v1 = p[1], v2 = p[2], v3 = p[3];
#pragma unroll
      for (int j = 0; j < 4; ++j) { va[j] = v0[j]; va[4 + j] = v1[j]; va[8 + j] = v2[j]; va[12 + j] = v3[j]; }
    } else {
#pragma unroll
      for (int j = 0; j < 16; ++j) va[j] = 0.0f;
    }
  };
  auto loadB = [&](int k0, s16x8* vb) {
#pragma unroll
    for (int c = 0; c < CH; ++c) {
      int ch = tid + c * 256;
      int br = ch >> 2;
      int bc = (ch & 3) << 3;
      vb[c] = *(const s16x8*)&Bt[(long long)br * KTOT + k0 + bc];
    }
  };

  float va[16];
  s16x8 vb[CH];
  loadA(0, va);
  loadB(0, vb);

  for (int k0 = 0; k0 < KTOT; k0 += BK) {
    // transform + pack current A regs
    float vt[16];
    if constexpr (MODE == 1) {
      const f32x4* bp = (const f32x4*)(bias + k0 + sc);
      f32x4 b0 = bp[0], b1 = bp[1], b2 = bp[2], b3 = bp[3];
      float vbias[16];
#pragma unroll
      for (int j = 0; j < 4; ++j) { vbias[j] = b0[j]; vbias[4 + j] = b1[j]; vbias[8 + j] = b2[j]; vbias[12 + j] = b3[j]; }
#pragma unroll
      for (int j = 0; j < 16; ++j) vt[j] = fmaxf(0.0f, vbias[j] + dv_a * va[j]);
    } else {
#pragma unroll
      for (int j = 0; j < 16; ++j) vt[j] = va[j];
    }
    s16x8 h0, h1;
#pragma unroll
    for (int j = 0; j < 8; ++j) { h0[j] = (short)f2bf(vt[j]); h1[j] = (short)f2bf(vt[8 + j]); }

    __syncthreads();   // previous iter's LDS reads done
    *(s16x8*)&Asm_[sr * LD + sc] = h0;
    *(s16x8*)&Asm_[sr * LD + sc + 8] = h1;
#pragma unroll
    for (int c = 0; c < CH; ++c) {
      int ch = tid + c * 256;
      int br = ch >> 2;
      int bc = (ch & 3) << 3;
      *(s16x8*)&Bsm_[br * LD + bc] = vb[c];
    }
    __syncthreads();

    // prefetch next tile while MFMAs run (hides HBM latency under compute)
    if (k0 + BK < KTOT) { loadA(k0 + BK, va); loadB(k0 + BK, vb); }

    s16x8 af[8], bf[NF];
#pragma unroll
    for (int mi = 0; mi < 8; ++mi) af[mi] = *(const s16x8*)&Asm_[(mi * 16 + fr) * LD + quad * 8];
#pragma unroll
    for (int ni = 0; ni < NF; ++ni) bf[ni] = *(const s16x8*)&Bsm_[(wave * STRIP + ni * 16 + fr) * LD + quad * 8];
#pragma unroll
    for (int mi = 0; mi < 8; ++mi)
#pragma unroll
      for (int ni = 0; ni < NF; ++ni)
        acc[mi][ni] = __builtin_amdgcn_mfma_f32_16x16x32_bf16(af[mi], bf[ni], acc[mi][ni], 0, 0, 0);
  }

  // epilogue: C/D layout col=lane&15, row=quad*4+r (m89/m91-verified)
#pragma unroll
  for (int mi = 0; mi < 8; ++mi) {
    int mbase = mi * 16 + quad * 4;
#pragma unroll
    for (int r = 0; r < 4; ++r) {
      int gm = m0 + mbase + r;
      if (gm < M) {
        float dv = dinv[gm];
#pragma unroll
        for (int ni = 0; ni < NF; ++ni) {
          int col = wave * STRIP + ni * 16 + fr;
          float val = acc[mi][ni][r] * dv;
          long long idx = (long long)gm * NTOT + col;
          outg[idx] = val;
          outacc[idx] = val;
        }
      }
    }
  }
}

// ---------------- edge scatter-add: acc[dst] += g[src], 256 feats (64 lanes x float4) ----------------
__global__ void scatter_k256(const int* __restrict__ edges, const float* __restrict__ g,
                             float* __restrict__ acc, int E) {
  const int lane = threadIdx.x & 63;
  const int f0 = lane << 2;
  const int wgl = blockIdx.x * 4 + (threadIdx.x >> 6);
  int e0 = wgl * 4;
#pragma unroll
  for (int i = 0; i < 4; ++i) {
    int e = e0 + i;
    if (e < E) {
      int s = edges[e], d = edges[E + e];
      f32x4 v = *(const f32x4*)&g[(long long)s * 256 + f0];
      float* p = &acc[(long long)d * 256 + f0];
      unsafeAtomicAdd(p + 0, v[0]);
      unsafeAtomicAdd(p + 1, v[1]);
      unsafeAtomicAdd(p + 2, v[2]);
      unsafeAtomicAdd(p + 3, v[3]);
    }
  }
}

// 128 feats (32 lanes x float4)
__global__ void scatter_k128(const int* __restrict__ edges, const float* __restrict__ g,
                             float* __restrict__ acc, int E) {
  const int lane = threadIdx.x & 31;
  const int f0 = lane << 2;
  const int grp = blockIdx.x * 8 + (threadIdx.x >> 5);
  int e0 = grp * 4;
#pragma unroll
  for (int i = 0; i < 4; ++i) {
    int e = e0 + i;
    if (e < E) {
      int s = edges[e], d = edges[E + e];
      f32x4 v = *(const f32x4*)&g[(long long)s * 128 + f0];
      float* p = &acc[(long long)d * 128 + f0];
      unsafeAtomicAdd(p + 0, v[0]);
      unsafeAtomicAdd(p + 1, v[1]);
      unsafeAtomicAdd(p + 2, v[2]);
      unsafeAtomicAdd(p + 3, v[3]);
    }
  }
}

// ---------------- out = normalize(b2 + dinv*acc2) ; one wave per row of 128 ----------------
__global__ void finalize_k(const float* __restrict__ acc2, const float* __restrict__ b2,
                           const float* __restrict__ dinv, float* __restrict__ out, int N) {
  int row = blockIdx.x * 4 + (threadIdx.x >> 6);
  int lane = threadIdx.x & 63;
  if (row >= N) return;
  float dv = dinv[row];
  f32x2 v = *(const f32x2*)&acc2[(long long)row * 128 + lane * 2];
  f32x2 b = *(const f32x2*)&b2[lane * 2];
  float x0 = b[0] + dv * v[0];
  float x1 = b[1] + dv * v[1];
  float ss = x0 * x0 + x1 * x1;
#pragma unroll
  for (int off = 32; off > 0; off >>= 1) ss += __shfl_xor(ss, off, 64);
  float inv = 1.0f / fmaxf(sqrtf(ss), 1e-12f);
  f32x2 o = {x0 * inv, x1 * inv};
  *(f32x2*)&out[(long long)row * 128 + lane * 2] = o;
}

extern "C" void kernel_launch(void* const* d_in, const int* in_sizes, int n_in,
                              void* d_out, int out_size, void* d_ws, size_t ws_size,
                              hipStream_t stream) {
  const float* x = (const float*)d_in[0];
  const int* edges = (const int*)d_in[1];
  const float* W1 = (const float*)d_in[2];
  const float* b1 = (const float*)d_in[3];
  const float* W2 = (const float*)d_in[4];
  const float* b2 = (const float*)d_in[5];
  float* out = (float*)d_out;

  const int HID = in_sizes[3];         // 256
  const int OUT = in_sizes[5];         // 128
  const int IN = in_sizes[2] / HID;    // 1536
  const int N = in_sizes[0] / IN;      // 50000
  const int E = in_sizes[1] / 2;       // 1600000

  size_t off = 0;
  auto carve = [&](size_t bytes) {
    void* p = (char*)d_ws + off;
    off += (bytes + 255) & ~(size_t)255;
    return p;
  };
  int* deg = (int*)carve((size_t)N * 4);
  float* dinv = (float*)carve((size_t)N * 4);
  unsigned short* W1t = (unsigned short*)carve((size_t)IN * HID * 2);
  unsigned short* W2t = (unsigned short*)carve((size_t)HID * OUT * 2);
  float* g1 = (float*)carve((size_t)N * HID * 4);
  float* acc1 = (float*)carve((size_t)N * HID * 4);
  float* g2 = (float*)carve((size_t)N * OUT * 4);
  float* acc2 = (float*)carve((size_t)N * OUT * 4);
  (void)ws_size; (void)n_in; (void)out_size;

  deg_init_k<<<(N + 255) / 256, 256, 0, stream>>>(deg, N);
  deg_count_k<<<(E + 255) / 256, 256, 0, stream>>>(edges, deg, E);
  dinv_k<<<(N + 255) / 256, 256, 0, stream>>>(deg, dinv, N);
  convw_k<<<(IN * HID + 255) / 256, 256, 0, stream>>>(W1, W1t, IN, HID);
  convw_k<<<(HID * OUT + 255) / 256, 256, 0, stream>>>(W2, W2t, HID, OUT);

  int mtiles = (N + 127) / 128;
  gemm_k<1536, 256, 0><<<mtiles, 256, 0, stream>>>(x, W1t, nullptr, dinv, g1, acc1, N);

  int sb1 = (E + 15) / 16;             // 4 waves/block, 4 edges/wave
  scatter_k256<<<sb1, 256, 0, stream>>>(edges, g1, acc1, E);

  gemm_k<256, 128, 1><<<mtiles, 256, 0, stream>>>(acc1, W2t, b1, dinv, g2, acc2, N);

  int sb2 = (E + 31) / 32;             // 8 groups/block, 4 edges/group
  scatter_k128<<<sb2, 256, 0, stream>>>(edges, g2, acc2, E);

  finalize_k<<<(N + 3) / 4, 256, 0, stream>>>(acc2, b2, dinv, out, N);
}

// Round 2
// 981.407 us; speedup vs baseline: 8.6913x; 8.6913x over previous
//
#include <hip/hip_runtime.h>

typedef __attribute__((ext_vector_type(4))) float f32x4;
typedef __attribute__((ext_vector_type(2))) float f32x2;
typedef __attribute__((ext_vector_type(8))) short s16x8;

static __device__ __forceinline__ unsigned short f2bf(float f) {
  unsigned int u = __builtin_bit_cast(unsigned int, f);
  u += 0x7fffu + ((u >> 16) & 1u);   // round-to-nearest-even
  return (unsigned short)(u >> 16);
}

// ---------------- utility ----------------
__global__ void zero_k(int* p, int n) {
  int i = blockIdx.x * 256 + threadIdx.x;
  if (i < n) p[i] = 0;
}
// cnt[d] = number of edges with dst==d (self-loops NOT included here)
__global__ void deg_count_k(const int* __restrict__ edges, int* cnt, int E) {
  int e = blockIdx.x * 256 + threadIdx.x;
  if (e < E) atomicAdd(&cnt[edges[E + e]], 1);
}
__global__ void dinv_k(const int* __restrict__ cnt, float* dinv, int N) {
  int i = blockIdx.x * 256 + threadIdx.x;
  if (i < N) dinv[i] = rsqrtf((float)(cnt[i] + 1));   // +1 self-loop
}

// ---------------- prefix scan (exclusive) over cnt -> row offsets ----------------
// k1: per-block (1024 elems) local exclusive scan into loc[], block total into bsum[]
__global__ __launch_bounds__(256) void scan1_k(const int* __restrict__ cnt,
                                               int* __restrict__ loc,
                                               int* __restrict__ bsum, int N) {
  int t = threadIdx.x;
  int i0 = blockIdx.x * 1024 + t * 4;
  int c[4];
#pragma unroll
  for (int j = 0; j < 4; ++j) c[j] = (i0 + j < N) ? cnt[i0 + j] : 0;
  int tsum = c[0] + c[1] + c[2] + c[3];
  int lane = t & 63, wv = t >> 6;
  int incl = tsum;
#pragma unroll
  for (int off = 1; off < 64; off <<= 1) {
    int u = __shfl_up(incl, off, 64);
    if (lane >= off) incl += u;
  }
  __shared__ int ws[4];
  if (lane == 63) ws[wv] = incl;
  __syncthreads();
  int wbase = 0;
  for (int w = 0; w < wv; ++w) wbase += ws[w];
  int run = wbase + incl - tsum;   // exclusive prefix of this thread's 4
#pragma unroll
  for (int j = 0; j < 4; ++j) {
    if (i0 + j < N) loc[i0 + j] = run;
    run += c[j];
  }
  if (t == 255) bsum[blockIdx.x] = wbase + incl;
}
// k2: exclusive scan of block sums (nb <= 64, one wave)
__global__ void scan2_k(int* bsum, int nb) {
  int lane = threadIdx.x;
  int v = (lane < nb) ? bsum[lane] : 0;
  int incl = v;
#pragma unroll
  for (int off = 1; off < 64; off <<= 1) {
    int u = __shfl_up(incl, off, 64);
    if (lane >= off) incl += u;
  }
  if (lane < nb) bsum[lane] = incl - v;
}
// k3: add block offsets in place
__global__ void addoff_k(int* loc, const int* __restrict__ bsum, int N) {
  int i = blockIdx.x * 256 + threadIdx.x;
  if (i < N) loc[i] += bsum[i >> 10];
}
// fill CSR: csr[row[d] + cursor[d]++] = src
__global__ void fill_k(const int* __restrict__ edges, const int* __restrict__ row,
                       int* cursor, int* __restrict__ csr, int E) {
  int e = blockIdx.x * 256 + threadIdx.x;
  if (e < E) {
    int s = edges[e], d = edges[E + e];
    int pos = atomicAdd(&cursor[d], 1);
    csr[row[d] + pos] = s;
  }
}

// ---------------- weight transpose + bf16 convert: Wt[n][k] = bf16(W[k][n]) ----------------
__global__ void convw_k(const float* __restrict__ W, unsigned short* __restrict__ Wt, int K, int Nn) {
  int t = blockIdx.x * 256 + threadIdx.x;
  if (t < K * Nn) {
    int n = t / K;
    int k = t - n * K;
    Wt[n * K + k] = f2bf(W[(long long)k * Nn + n]);
  }
}

// ---------------- bf16 MFMA GEMM: outg[m][n] = dinv[m] * (A @ Bt^T)[m][n] ----------------
template <int KTOT, int NTOT>
__global__ __launch_bounds__(256, 2) void gemm_k(
    const float* __restrict__ A, const unsigned short* __restrict__ Bt,
    const float* __restrict__ dinv, float* __restrict__ outg, int M) {
  constexpr int BM = 128, BK = 32, LD = BK + 8;
  constexpr int STRIP = NTOT / 4;
  constexpr int NF = STRIP / 16;
  constexpr int CH = NTOT / 64;

  __shared__ unsigned short Asm_[BM * LD];
  __shared__ unsigned short Bsm_[NTOT * LD];

  const int tid = threadIdx.x;
  const int wave = tid >> 6;
  const int lane = tid & 63;
  const int fr = lane & 15;
  const int quad = lane >> 4;
  const int m0 = blockIdx.x * BM;

  f32x4 acc[8][NF];
#pragma unroll
  for (int i = 0; i < 8; ++i)
#pragma unroll
    for (int j = 0; j < NF; ++j) { f32x4 z = {0.f, 0.f, 0.f, 0.f}; acc[i][j] = z; }

  const int sr = tid >> 1;
  const int sc = (tid & 1) << 4;
  const bool arow_ok = (m0 + sr) < M;
  const float* arow = A + (long long)(m0 + sr) * KTOT;

  auto loadA = [&](int k0, float* va) {
    if (arow_ok) {
      const f32x4* p = (const f32x4*)(arow + k0 + sc);
      f32x4 v0 = p[0], v1 = p[1], v2 = p[2], v3 = p[3];
#pragma unroll
      for (int j = 0; j < 4; ++j) { va[j] = v0[j]; va[4 + j] = v1[j]; va[8 + j] = v2[j]; va[12 + j] = v3[j]; }
    } else {
#pragma unroll
      for (int j = 0; j < 16; ++j) va[j] = 0.0f;
    }
  };
  auto loadB = [&](int k0, s16x8* vb) {
#pragma unroll
    for (int c = 0; c < CH; ++c) {
      int ch = tid + c * 256;
      int br = ch >> 2;
      int bc = (ch & 3) << 3;
      vb[c] = *(const s16x8*)&Bt[(long long)br * KTOT + k0 + bc];
    }
  };

  float va[16];
  s16x8 vb[CH];
  loadA(0, va);
  loadB(0, vb);

  for (int k0 = 0; k0 < KTOT; k0 += BK) {
    s16x8 h0, h1;
#pragma unroll
    for (int j = 0; j < 8; ++j) { h0[j] = (short)f2bf(va[j]); h1[j] = (short)f2bf(va[8 + j]); }

    __syncthreads();
    *(s16x8*)&Asm_[sr * LD + sc] = h0;
    *(s16x8*)&Asm_[sr * LD + sc + 8] = h1;
#pragma unroll
    for (int c = 0; c < CH; ++c) {
      int ch = tid + c * 256;
      int br = ch >> 2;
      int bc = (ch & 3) << 3;
      *(s16x8*)&Bsm_[br * LD + bc] = vb[c];
    }
    __syncthreads();

    if (k0 + BK < KTOT) { loadA(k0 + BK, va); loadB(k0 + BK, vb); }

    s16x8 af[8], bfr[NF];
#pragma unroll
    for (int mi = 0; mi < 8; ++mi) af[mi] = *(const s16x8*)&Asm_[(mi * 16 + fr) * LD + quad * 8];
#pragma unroll
    for (int ni = 0; ni < NF; ++ni) bfr[ni] = *(const s16x8*)&Bsm_[(wave * STRIP + ni * 16 + fr) * LD + quad * 8];
#pragma unroll
    for (int mi = 0; mi < 8; ++mi)
#pragma unroll
      for (int ni = 0; ni < NF; ++ni)
        acc[mi][ni] = __builtin_amdgcn_mfma_f32_16x16x32_bf16(af[mi], bfr[ni], acc[mi][ni], 0, 0, 0);
  }

#pragma unroll
  for (int mi = 0; mi < 8; ++mi) {
    int mbase = mi * 16 + quad * 4;
#pragma unroll
    for (int r = 0; r < 4; ++r) {
      int gm = m0 + mbase + r;
      if (gm < M) {
        float dv = dinv[gm];
#pragma unroll
        for (int ni = 0; ni < NF; ++ni) {
          int col = wave * STRIP + ni * 16 + fr;
          outg[(long long)gm * NTOT + col] = acc[mi][ni][r] * dv;
        }
      }
    }
  }
}

// ---------------- agg layer 1: h[d] = relu(b1 + dinv[d]*(g[d] + sum_{src in csr[d]} g[src])) ----------------
// 256 feats, one wave per node, f32x4 per lane
__global__ __launch_bounds__(256) void agg1_k(const int* __restrict__ csr,
                                              const int* __restrict__ row,
                                              const int* __restrict__ cnt,
                                              const float* __restrict__ g,
                                              const float* __restrict__ bias,
                                              const float* __restrict__ dinv,
                                              float* __restrict__ h, int N) {
  int node = blockIdx.x * 4 + (threadIdx.x >> 6);
  if (node >= N) return;
  int lane = threadIdx.x & 63;
  int f0 = lane << 2;
  f32x4 s = *(const f32x4*)&g[(long long)node * 256 + f0];   // self-loop term
  int start = row[node], len = cnt[node];
  int j = 0;
  for (; j + 4 <= len; j += 4) {
    int i0 = csr[start + j], i1 = csr[start + j + 1];
    int i2 = csr[start + j + 2], i3 = csr[start + j + 3];
    f32x4 v0 = *(const f32x4*)&g[(long long)i0 * 256 + f0];
    f32x4 v1 = *(const f32x4*)&g[(long long)i1 * 256 + f0];
    f32x4 v2 = *(const f32x4*)&g[(long long)i2 * 256 + f0];
    f32x4 v3 = *(const f32x4*)&g[(long long)i3 * 256 + f0];
    s += v0; s += v1; s += v2; s += v3;
  }
  for (; j < len; ++j) {
    int i0 = csr[start + j];
    s += *(const f32x4*)&g[(long long)i0 * 256 + f0];
  }
  float dv = dinv[node];
  f32x4 b = *(const f32x4*)&bias[f0];
  f32x4 o;
#pragma unroll
  for (int k = 0; k < 4; ++k) o[k] = fmaxf(0.0f, b[k] + dv * s[k]);
  *(f32x4*)&h[(long long)node * 256 + f0] = o;
}

// ---------------- agg layer 2 + L2-normalize fused: out[d] = normalize(b2 + dinv[d]*sum) ----------------
// 128 feats, one wave per node, f32x2 per lane
__global__ __launch_bounds__(256) void agg2_k(const int* __restrict__ csr,
                                              const int* __restrict__ row,
                                              const int* __restrict__ cnt,
                                              const float* __restrict__ g,
                                              const float* __restrict__ b2,
                                              const float* __restrict__ dinv,
                                              float* __restrict__ out, int N) {
  int node = blockIdx.x * 4 + (threadIdx.x >> 6);
  if (node >= N) return;
  int lane = threadIdx.x & 63;
  int f0 = lane << 1;
  f32x2 s = *(const f32x2*)&g[(long long)node * 128 + f0];
  int start = row[node], len = cnt[node];
  int j = 0;
  for (; j + 4 <= len; j += 4) {
    int i0 = csr[start + j], i1 = csr[start + j + 1];
    int i2 = csr[start + j + 2], i3 = csr[start + j + 3];
    f32x2 v0 = *(const f32x2*)&g[(long long)i0 * 128 + f0];
    f32x2 v1 = *(const f32x2*)&g[(long long)i1 * 128 + f0];
    f32x2 v2 = *(const f32x2*)&g[(long long)i2 * 128 + f0];
    f32x2 v3 = *(const f32x2*)&g[(long long)i3 * 128 + f0];
    s += v0; s += v1; s += v2; s += v3;
  }
  for (; j < len; ++j) {
    int i0 = csr[start + j];
    s += *(const f32x2*)&g[(long long)i0 * 128 + f0];
  }
  float dv = dinv[node];
  f32x2 b = *(const f32x2*)&b2[f0];
  float x0 = b[0] + dv * s[0];
  float x1 = b[1] + dv * s[1];
  float ss = x0 * x0 + x1 * x1;
#pragma unroll
  for (int off = 32; off > 0; off >>= 1) ss += __shfl_xor(ss, off, 64);
  float inv = 1.0f / fmaxf(sqrtf(ss), 1e-12f);
  f32x2 o = {x0 * inv, x1 * inv};
  *(f32x2*)&out[(long long)node * 128 + f0] = o;
}

extern "C" void kernel_launch(void* const* d_in, const int* in_sizes, int n_in,
                              void* d_out, int out_size, void* d_ws, size_t ws_size,
                              hipStream_t stream) {
  const float* x = (const float*)d_in[0];
  const int* edges = (const int*)d_in[1];
  const float* W1 = (const float*)d_in[2];
  const float* b1 = (const float*)d_in[3];
  const float* W2 = (const float*)d_in[4];
  const float* b2 = (const float*)d_in[5];
  float* out = (float*)d_out;

  const int HID = in_sizes[3];          // 256
  const int OUT = in_sizes[5];          // 128
  const int IN = in_sizes[2] / HID;     // 1536
  const int N = in_sizes[0] / IN;       // 50000
  const int E = in_sizes[1] / 2;        // 1600000

  size_t off = 0;
  auto carve = [&](size_t bytes) {
    void* p = (char*)d_ws + off;
    off += (bytes + 255) & ~(size_t)255;
    return p;
  };
  int* cnt = (int*)carve((size_t)N * 4);
  int* cursor = (int*)carve((size_t)N * 4);
  int* row = (int*)carve((size_t)N * 4);
  int* bsum = (int*)carve(64 * 4);
  int* csr = (int*)carve((size_t)E * 4);
  float* dinv = (float*)carve((size_t)N * 4);
  unsigned short* W1t = (unsigned short*)carve((size_t)IN * HID * 2);
  unsigned short* W2t = (unsigned short*)carve((size_t)HID * OUT * 2);
  float* g1 = (float*)carve((size_t)N * HID * 4);
  float* acc1 = (float*)carve((size_t)N * HID * 4);
  float* g2 = (float*)carve((size_t)N * OUT * 4);
  (void)ws_size; (void)n_in; (void)out_size;

  const int nb = (N + 1023) / 1024;

  zero_k<<<(N + 255) / 256, 256, 0, stream>>>(cnt, N);
  zero_k<<<(N + 255) / 256, 256, 0, stream>>>(cursor, N);
  deg_count_k<<<(E + 255) / 256, 256, 0, stream>>>(edges, cnt, E);
  dinv_k<<<(N + 255) / 256, 256, 0, stream>>>(cnt, dinv, N);

  scan1_k<<<nb, 256, 0, stream>>>(cnt, row, bsum, N);
  scan2_k<<<1, 64, 0, stream>>>(bsum, nb);
  addoff_k<<<(N + 255) / 256, 256, 0, stream>>>(row, bsum, N);
  fill_k<<<(E + 255) / 256, 256, 0, stream>>>(edges, row, cursor, csr, E);

  convw_k<<<(IN * HID + 255) / 256, 256, 0, stream>>>(W1, W1t, IN, HID);
  convw_k<<<(HID * OUT + 255) / 256, 256, 0, stream>>>(W2, W2t, HID, OUT);

  int mtiles = (N + 127) / 128;
  gemm_k<1536, 256><<<mtiles, 256, 0, stream>>>(x, W1t, dinv, g1, N);
  agg1_k<<<(N + 3) / 4, 256, 0, stream>>>(csr, row, cnt, g1, b1, dinv, acc1, N);
  gemm_k<256, 128><<<mtiles, 256, 0, stream>>>(acc1, W2t, dinv, g2, N);
  agg2_k<<<(N + 3) / 4, 256, 0, stream>>>(csr, row, cnt, g2, b2, dinv, out, N);
}

// Round 3
// 814.388 us; speedup vs baseline: 10.4737x; 1.2051x over previous
//
#include <hip/hip_runtime.h>

typedef __attribute__((ext_vector_type(4))) float f32x4;
typedef __attribute__((ext_vector_type(2))) float f32x2;
typedef __attribute__((ext_vector_type(8))) short s16x8;
typedef __attribute__((ext_vector_type(4))) unsigned short u16x4;
typedef __attribute__((ext_vector_type(2))) unsigned short u16x2;

static __device__ __forceinline__ unsigned short f2bf(float f) {
  unsigned int u = __builtin_bit_cast(unsigned int, f);
  u += 0x7fffu + ((u >> 16) & 1u);   // round-to-nearest-even
  return (unsigned short)(u >> 16);
}
static __device__ __forceinline__ float bf2f(unsigned short h) {
  unsigned int u = ((unsigned int)h) << 16;
  return __builtin_bit_cast(float, u);
}

// ---------------- utility ----------------
__global__ void zero_k(int* p, int n) {
  int i = blockIdx.x * 256 + threadIdx.x;
  if (i < n) p[i] = 0;
}
__global__ void deg_count_k(const int* __restrict__ edges, int* cnt, int E) {
  int e = blockIdx.x * 256 + threadIdx.x;
  if (e < E) atomicAdd(&cnt[edges[E + e]], 1);
}
__global__ void dinv_k(const int* __restrict__ cnt, float* dinv, int N) {
  int i = blockIdx.x * 256 + threadIdx.x;
  if (i < N) dinv[i] = rsqrtf((float)(cnt[i] + 1));   // +1 self-loop
}

// ---------------- prefix scan (exclusive) over cnt -> row offsets ----------------
__global__ __launch_bounds__(256) void scan1_k(const int* __restrict__ cnt,
                                               int* __restrict__ loc,
                                               int* __restrict__ bsum, int N) {
  int t = threadIdx.x;
  int i0 = blockIdx.x * 1024 + t * 4;
  int c[4];
#pragma unroll
  for (int j = 0; j < 4; ++j) c[j] = (i0 + j < N) ? cnt[i0 + j] : 0;
  int tsum = c[0] + c[1] + c[2] + c[3];
  int lane = t & 63, wv = t >> 6;
  int incl = tsum;
#pragma unroll
  for (int off = 1; off < 64; off <<= 1) {
    int u = __shfl_up(incl, off, 64);
    if (lane >= off) incl += u;
  }
  __shared__ int ws[4];
  if (lane == 63) ws[wv] = incl;
  __syncthreads();
  int wbase = 0;
  for (int w = 0; w < wv; ++w) wbase += ws[w];
  int run = wbase + incl - tsum;
#pragma unroll
  for (int j = 0; j < 4; ++j) {
    if (i0 + j < N) loc[i0 + j] = run;
    run += c[j];
  }
  if (t == 255) bsum[blockIdx.x] = wbase + incl;
}
__global__ void scan2_k(int* bsum, int nb) {
  int lane = threadIdx.x;
  int v = (lane < nb) ? bsum[lane] : 0;
  int incl = v;
#pragma unroll
  for (int off = 1; off < 64; off <<= 1) {
    int u = __shfl_up(incl, off, 64);
    if (lane >= off) incl += u;
  }
  if (lane < nb) bsum[lane] = incl - v;
}
__global__ void addoff_k(int* loc, const int* __restrict__ bsum, int N) {
  int i = blockIdx.x * 256 + threadIdx.x;
  if (i < N) loc[i] += bsum[i >> 10];
}
__global__ void fill_k(const int* __restrict__ edges, const int* __restrict__ row,
                       int* cursor, int* __restrict__ csr, int E) {
  int e = blockIdx.x * 256 + threadIdx.x;
  if (e < E) {
    int s = edges[e], d = edges[E + e];
    int pos = atomicAdd(&cursor[d], 1);
    csr[row[d] + pos] = s;
  }
}

// ---------------- weight transpose + bf16 convert: Wt[n][k] = bf16(W[k][n]) ----------------
__global__ void convw_k(const float* __restrict__ W, unsigned short* __restrict__ Wt, int K, int Nn) {
  int t = blockIdx.x * 256 + threadIdx.x;
  if (t < K * Nn) {
    int n = t / K;
    int k = t - n * K;
    Wt[n * K + k] = f2bf(W[(long long)k * Nn + n]);
  }
}

// ---------------- bf16 MFMA GEMM: outg[m][n] = bf16( dinv[m] * (A @ Bt^T)[m][n] ) ----------------
// A_BF16=false: A fp32 (layer 1, A=x). A_BF16=true: A bf16 (layer 2, A=acc1).
template <int KTOT, int NTOT, bool A_BF16>
__global__ __launch_bounds__(256, 2) void gemm_k(
    const void* __restrict__ Aptr, const unsigned short* __restrict__ Bt,
    const float* __restrict__ dinv, unsigned short* __restrict__ outg, int M) {
  constexpr int BM = 128, BK = 32, LD = BK + 8;
  constexpr int STRIP = NTOT / 4;
  constexpr int NF = STRIP / 16;
  constexpr int CH = NTOT / 64;

  __shared__ unsigned short Asm_[BM * LD];
  __shared__ unsigned short Bsm_[NTOT * LD];

  const int tid = threadIdx.x;
  const int wave = tid >> 6;
  const int lane = tid & 63;
  const int fr = lane & 15;
  const int quad = lane >> 4;
  const int m0 = blockIdx.x * BM;

  f32x4 acc[8][NF];
#pragma unroll
  for (int i = 0; i < 8; ++i)
#pragma unroll
    for (int j = 0; j < NF; ++j) { f32x4 z = {0.f, 0.f, 0.f, 0.f}; acc[i][j] = z; }

  const int sr = tid >> 1;
  const int sc = (tid & 1) << 4;
  const bool arow_ok = (m0 + sr) < M;
  const float* arowf = (const float*)Aptr + (long long)(m0 + sr) * KTOT;
  const unsigned short* arowh = (const unsigned short*)Aptr + (long long)(m0 + sr) * KTOT;

  float va[16];
  s16x8 vah[2];

  auto loadA = [&](int k0) {
    if constexpr (A_BF16) {
      if (arow_ok) {
        vah[0] = *(const s16x8*)(arowh + k0 + sc);
        vah[1] = *(const s16x8*)(arowh + k0 + sc + 8);
      } else {
        s16x8 z = {0, 0, 0, 0, 0, 0, 0, 0};
        vah[0] = z; vah[1] = z;
      }
    } else {
      if (arow_ok) {
        const f32x4* p = (const f32x4*)(arowf + k0 + sc);
        f32x4 v0 = p[0], v1 = p[1], v2 = p[2], v3 = p[3];
#pragma unroll
        for (int j = 0; j < 4; ++j) { va[j] = v0[j]; va[4 + j] = v1[j]; va[8 + j] = v2[j]; va[12 + j] = v3[j]; }
      } else {
#pragma unroll
        for (int j = 0; j < 16; ++j) va[j] = 0.0f;
      }
    }
  };
  s16x8 vb[CH];
  auto loadB = [&](int k0) {
#pragma unroll
    for (int c = 0; c < CH; ++c) {
      int ch = tid + c * 256;
      int br = ch >> 2;
      int bc = (ch & 3) << 3;
      vb[c] = *(const s16x8*)&Bt[(long long)br * KTOT + k0 + bc];
    }
  };

  loadA(0);
  loadB(0);

  for (int k0 = 0; k0 < KTOT; k0 += BK) {
    s16x8 h0, h1;
    if constexpr (A_BF16) {
      h0 = vah[0]; h1 = vah[1];
    } else {
#pragma unroll
      for (int j = 0; j < 8; ++j) { h0[j] = (short)f2bf(va[j]); h1[j] = (short)f2bf(va[8 + j]); }
    }
    s16x8 vbc[CH];
#pragma unroll
    for (int c = 0; c < CH; ++c) vbc[c] = vb[c];

    __syncthreads();
    *(s16x8*)&Asm_[sr * LD + sc] = h0;
    *(s16x8*)&Asm_[sr * LD + sc + 8] = h1;
#pragma unroll
    for (int c = 0; c < CH; ++c) {
      int ch = tid + c * 256;
      int br = ch >> 2;
      int bc = (ch & 3) << 3;
      *(s16x8*)&Bsm_[br * LD + bc] = vbc[c];
    }
    __syncthreads();

    if (k0 + BK < KTOT) { loadA(k0 + BK); loadB(k0 + BK); }

    s16x8 af[8], bfr[NF];
#pragma unroll
    for (int mi = 0; mi < 8; ++mi) af[mi] = *(const s16x8*)&Asm_[(mi * 16 + fr) * LD + quad * 8];
#pragma unroll
    for (int ni = 0; ni < NF; ++ni) bfr[ni] = *(const s16x8*)&Bsm_[(wave * STRIP + ni * 16 + fr) * LD + quad * 8];
#pragma unroll
    for (int mi = 0; mi < 8; ++mi)
#pragma unroll
      for (int ni = 0; ni < NF; ++ni)
        acc[mi][ni] = __builtin_amdgcn_mfma_f32_16x16x32_bf16(af[mi], bfr[ni], acc[mi][ni], 0, 0, 0);
  }

  // C/D layout: col=lane&15, row=quad*4+r
#pragma unroll
  for (int mi = 0; mi < 8; ++mi) {
    int mbase = mi * 16 + quad * 4;
#pragma unroll
    for (int r = 0; r < 4; ++r) {
      int gm = m0 + mbase + r;
      if (gm < M) {
        float dv = dinv[gm];
#pragma unroll
        for (int ni = 0; ni < NF; ++ni) {
          int col = wave * STRIP + ni * 16 + fr;
          outg[(long long)gm * NTOT + col] = f2bf(acc[mi][ni][r] * dv);
        }
      }
    }
  }
}

// ---------------- agg layer 1 (bf16 msgs): acc1[d] = bf16(relu(b1 + dinv[d]*(g[d] + sum g[src]))) ----------------
__global__ __launch_bounds__(256) void agg1_k(const int* __restrict__ csr,
                                              const int* __restrict__ row,
                                              const int* __restrict__ cnt,
                                              const unsigned short* __restrict__ g,
                                              const float* __restrict__ bias,
                                              const float* __restrict__ dinv,
                                              unsigned short* __restrict__ h, int N) {
  int node = blockIdx.x * 4 + (threadIdx.x >> 6);
  if (node >= N) return;
  int lane = threadIdx.x & 63;
  int f0 = lane << 2;
  u16x4 sv = *(const u16x4*)&g[(long long)node * 256 + f0];
  f32x4 s = {bf2f(sv[0]), bf2f(sv[1]), bf2f(sv[2]), bf2f(sv[3])};
  int start = row[node], len = cnt[node];
  int j = 0;
  for (; j + 8 <= len; j += 8) {
    int idx[8];
#pragma unroll
    for (int t = 0; t < 8; ++t) idx[t] = csr[start + j + t];
    u16x4 v[8];
#pragma unroll
    for (int t = 0; t < 8; ++t) v[t] = *(const u16x4*)&g[(long long)idx[t] * 256 + f0];
#pragma unroll
    for (int t = 0; t < 8; ++t) {
      s[0] += bf2f(v[t][0]); s[1] += bf2f(v[t][1]);
      s[2] += bf2f(v[t][2]); s[3] += bf2f(v[t][3]);
    }
  }
  for (; j < len; ++j) {
    int i0 = csr[start + j];
    u16x4 v = *(const u16x4*)&g[(long long)i0 * 256 + f0];
    s[0] += bf2f(v[0]); s[1] += bf2f(v[1]); s[2] += bf2f(v[2]); s[3] += bf2f(v[3]);
  }
  float dv = dinv[node];
  f32x4 b = *(const f32x4*)&bias[f0];
  u16x4 o;
#pragma unroll
  for (int k = 0; k < 4; ++k) o[k] = f2bf(fmaxf(0.0f, b[k] + dv * s[k]));
  *(u16x4*)&h[(long long)node * 256 + f0] = o;
}

// ---------------- agg layer 2 + L2-normalize fused (bf16 msgs): out fp32 ----------------
__global__ __launch_bounds__(256) void agg2_k(const int* __restrict__ csr,
                                              const int* __restrict__ row,
                                              const int* __restrict__ cnt,
                                              const unsigned short* __restrict__ g,
                                              const float* __restrict__ b2,
                                              const float* __restrict__ dinv,
                                              float* __restrict__ out, int N) {
  int node = blockIdx.x * 4 + (threadIdx.x >> 6);
  if (node >= N) return;
  int lane = threadIdx.x & 63;
  int f0 = lane << 1;
  u16x2 sv = *(const u16x2*)&g[(long long)node * 128 + f0];
  float s0 = bf2f(sv[0]), s1 = bf2f(sv[1]);
  int start = row[node], len = cnt[node];
  int j = 0;
  for (; j + 8 <= len; j += 8) {
    int idx[8];
#pragma unroll
    for (int t = 0; t < 8; ++t) idx[t] = csr[start + j + t];
    u16x2 v[8];
#pragma unroll
    for (int t = 0; t < 8; ++t) v[t] = *(const u16x2*)&g[(long long)idx[t] * 128 + f0];
#pragma unroll
    for (int t = 0; t < 8; ++t) { s0 += bf2f(v[t][0]); s1 += bf2f(v[t][1]); }
  }
  for (; j < len; ++j) {
    int i0 = csr[start + j];
    u16x2 v = *(const u16x2*)&g[(long long)i0 * 128 + f0];
    s0 += bf2f(v[0]); s1 += bf2f(v[1]);
  }
  float dv = dinv[node];
  f32x2 b = *(const f32x2*)&b2[f0];
  float x0 = b[0] + dv * s0;
  float x1 = b[1] + dv * s1;
  float ss = x0 * x0 + x1 * x1;
#pragma unroll
  for (int off = 32; off > 0; off >>= 1) ss += __shfl_xor(ss, off, 64);
  float inv = 1.0f / fmaxf(sqrtf(ss), 1e-12f);
  f32x2 o = {x0 * inv, x1 * inv};
  *(f32x2*)&out[(long long)node * 128 + f0] = o;
}

extern "C" void kernel_launch(void* const* d_in, const int* in_sizes, int n_in,
                              void* d_out, int out_size, void* d_ws, size_t ws_size,
                              hipStream_t stream) {
  const float* x = (const float*)d_in[0];
  const int* edges = (const int*)d_in[1];
  const float* W1 = (const float*)d_in[2];
  const float* b1 = (const float*)d_in[3];
  const float* W2 = (const float*)d_in[4];
  const float* b2 = (const float*)d_in[5];
  float* out = (float*)d_out;

  const int HID = in_sizes[3];          // 256
  const int OUT = in_sizes[5];          // 128
  const int IN = in_sizes[2] / HID;     // 1536
  const int N = in_sizes[0] / IN;       // 50000
  const int E = in_sizes[1] / 2;        // 1600000

  size_t off = 0;
  auto carve = [&](size_t bytes) {
    void* p = (char*)d_ws + off;
    off += (bytes + 255) & ~(size_t)255;
    return p;
  };
  int* cnt = (int*)carve((size_t)N * 4);
  int* cursor = (int*)carve((size_t)N * 4);
  int* row = (int*)carve((size_t)N * 4);
  int* bsum = (int*)carve(64 * 4);
  int* csr = (int*)carve((size_t)E * 4);
  float* dinv = (float*)carve((size_t)N * 4);
  unsigned short* W1t = (unsigned short*)carve((size_t)IN * HID * 2);
  unsigned short* W2t = (unsigned short*)carve((size_t)HID * OUT * 2);
  unsigned short* g1 = (unsigned short*)carve((size_t)N * HID * 2);
  unsigned short* acc1 = (unsigned short*)carve((size_t)N * HID * 2);
  unsigned short* g2 = (unsigned short*)carve((size_t)N * OUT * 2);
  (void)ws_size; (void)n_in; (void)out_size;

  const int nb = (N + 1023) / 1024;

  zero_k<<<(N + 255) / 256, 256, 0, stream>>>(cnt, N);
  zero_k<<<(N + 255) / 256, 256, 0, stream>>>(cursor, N);
  deg_count_k<<<(E + 255) / 256, 256, 0, stream>>>(edges, cnt, E);
  dinv_k<<<(N + 255) / 256, 256, 0, stream>>>(cnt, dinv, N);

  scan1_k<<<nb, 256, 0, stream>>>(cnt, row, bsum, N);
  scan2_k<<<1, 64, 0, stream>>>(bsum, nb);
  addoff_k<<<(N + 255) / 256, 256, 0, stream>>>(row, bsum, N);
  fill_k<<<(E + 255) / 256, 256, 0, stream>>>(edges, row, cursor, csr, E);

  convw_k<<<(IN * HID + 255) / 256, 256, 0, stream>>>(W1, W1t, IN, HID);
  convw_k<<<(HID * OUT + 255) / 256, 256, 0, stream>>>(W2, W2t, HID, OUT);

  int mtiles = (N + 127) / 128;
  gemm_k<1536, 256, false><<<mtiles, 256, 0, stream>>>(x, W1t, dinv, g1, N);
  agg1_k<<<(N + 3) / 4, 256, 0, stream>>>(csr, row, cnt, g1, b1, dinv, acc1, N);
  gemm_k<256, 128, true><<<mtiles, 256, 0, stream>>>(acc1, W2t, dinv, g2, N);
  agg2_k<<<(N + 3) / 4, 256, 0, stream>>>(csr, row, cnt, g2, b2, dinv, out, N);
}